// Round 13
// baseline (51.622 us; speedup 1.0000x reference)
//
#include <hip/hip_runtime.h>

#define NE    32
#define DIN   256
#define DOUT  256
#define TN    32     // output cols per block
#define SPL   4      // token-split factor
#define XSTR  264    // u16 stride (256 + 8 pad)
#define REP   8      // DIAGNOSTIC: repeat main loop (idempotent) to cross rocprof top-5 cutoff

typedef __attribute__((ext_vector_type(8))) short short8v;   // 8 bf16 = 4 VGPR
typedef __attribute__((ext_vector_type(4))) float float4v;   // MFMA accumulator

__device__ __forceinline__ unsigned short f2bf(float f) {
    // fp32 -> bf16 round-to-nearest-even (inputs finite); verified R10 (absmax 0.031)
    unsigned u = __float_as_uint(f);
    return (unsigned short)((u + 0x7FFFu + ((u >> 16) & 1u)) >> 16);
}

// Kernel 1: per-expert deterministic ballot-scan routing, written ONCE to d_ws.
// toklist order = ascending token id (pure function of idx) -> deterministic.
__global__ __launch_bounds__(256) void route_kernel(const int* __restrict__ idx,
                                                    int* __restrict__ cnt,
                                                    unsigned short* __restrict__ tok) {
    __shared__ int wcnt[4][4];   // [round][wave]
    const int tid  = threadIdx.x;
    const int e    = blockIdx.x;
    const int lane = tid & 63;
    const int wid  = tid >> 6;
    const unsigned long long lt = (1ull << lane) - 1ull;
    unsigned short* tl = tok + e * 4096;

    int running = 0;
#pragma unroll
    for (int r = 0; r < 4; ++r) {
        const int tb = r * 1024 + tid * 4;
        const int4 v = *reinterpret_cast<const int4*>(idx + tb);
        const unsigned long long m0 = __ballot(v.x == e);
        const unsigned long long m1 = __ballot(v.y == e);
        const unsigned long long m2 = __ballot(v.z == e);
        const unsigned long long m3 = __ballot(v.w == e);
        const int p0 = __popcll(m0), p1 = __popcll(m1), p2 = __popcll(m2), p3 = __popcll(m3);
        if (lane == 0) wcnt[r][wid] = p0 + p1 + p2 + p3;
        __syncthreads();   // wcnt[r] slots never alias across rounds -> 1 barrier/round
        int wb = running;
        if (wid > 0) wb += wcnt[r][0];
        if (wid > 1) wb += wcnt[r][1];
        if (wid > 2) wb += wcnt[r][2];
        const int b0 = wb, b1 = b0 + p0, b2 = b1 + p1, b3 = b2 + p2;
        if (v.x == e) tl[b0 + __popcll(m0 & lt)] = (unsigned short)(tb + 0);
        if (v.y == e) tl[b1 + __popcll(m1 & lt)] = (unsigned short)(tb + 1);
        if (v.z == e) tl[b2 + __popcll(m2 & lt)] = (unsigned short)(tb + 2);
        if (v.w == e) tl[b3 + __popcll(m3 & lt)] = (unsigned short)(tb + 3);
        running += wcnt[r][0] + wcnt[r][1] + wcnt[r][2] + wcnt[r][3];
    }
    if (tid == 0) cnt[e] = running;
}

// Kernel 2: block = (split, expert, col-slice), grid 1024. No routing work:
// one cnt[e] load (workless blocks exit immediately), W panel -> bf16 LDS,
// then the barrier-free register-gather MFMA loop (R12 structure).
__global__ __launch_bounds__(256, 4) void gemm_kernel(
    const float* __restrict__ x, const float* __restrict__ w,
    const float* __restrict__ bias, const int* __restrict__ cnt,
    const unsigned short* __restrict__ tok, float* __restrict__ out)
{
    __shared__ unsigned short wls[TN * XSTR];   // 16896 B [col][k] bf16 (transposed)

    const int tid   = threadIdx.x;
    const int e     = blockIdx.x & 31;          // XCD = bx%8 = e%8
    const int cb    = (blockIdx.x >> 5) & 7;
    const int s     = blockIdx.x >> 8;
    const int obase = cb * TN;

    const int ce = cnt[e];
    if (ce <= s * 64) return;   // block-uniform: this split has no token groups

    // ---- stage W panel -> bf16, transposed [col][k]; thread t handles k = t ----
    {
        const float* wr = w + (size_t)e * DIN * DOUT + (size_t)tid * DOUT + obase;
#pragma unroll
        for (int j = 0; j < 8; ++j) {
            const float4 q = *reinterpret_cast<const float4*>(wr + j * 4);
            wls[(j * 4 + 0) * XSTR + tid] = f2bf(q.x);
            wls[(j * 4 + 1) * XSTR + tid] = f2bf(q.y);
            wls[(j * 4 + 2) * XSTR + tid] = f2bf(q.z);
            wls[(j * 4 + 3) * XSTR + tid] = f2bf(q.w);
        }
    }
    __syncthreads();

    // fragment lane roles (16x16x32 bf16):
    //   A: row = lane&15, k = (lane>>4)*8 + i  (8 consecutive -> 2 float4 from global)
    //   B: col = lane&15, k = (lane>>4)*8 + i  (b128 from wls)
    //   C/D: col = lane&15, row = (lane>>4)*4 + reg
    const int lane = tid & 63;
    const int wid  = tid >> 6;
    const int a15  = lane & 15;
    const int kg   = lane >> 4;
    const float bv0 = bias[(size_t)e * DOUT + obase + a15];
    const float bv1 = bias[(size_t)e * DOUT + obase + 16 + a15];
    const unsigned short* bw0 = &wls[a15 * XSTR];
    const unsigned short* bw1 = &wls[(16 + a15) * XSTR];
    const unsigned short* tl  = tok + e * 4096;

#pragma unroll 1
    for (int rep = 0; rep < REP; ++rep) {
#pragma unroll 1
        for (int tb0 = (s * 4 + wid) * 16; tb0 < ce; tb0 += SPL * 64) {
            const int tokid = tl[min(tb0 + a15, ce - 1)];
            const float* xr = x + (size_t)tokid * DIN + kg * 8;

            float4 L[16];   // 16 independent dwordx4 -> one latency exposure
#pragma unroll
            for (int kk = 0; kk < 8; ++kk) {
                L[2 * kk]     = *reinterpret_cast<const float4*>(xr + kk * 32);
                L[2 * kk + 1] = *reinterpret_cast<const float4*>(xr + kk * 32 + 4);
            }

            float4v acc0 = {0.f, 0.f, 0.f, 0.f};
            float4v acc1 = {0.f, 0.f, 0.f, 0.f};
#pragma unroll
            for (int kk = 0; kk < 8; ++kk) {
                const float4 u0 = L[2 * kk], u1 = L[2 * kk + 1];
                short8v a;
                a[0] = (short)f2bf(u0.x); a[1] = (short)f2bf(u0.y);
                a[2] = (short)f2bf(u0.z); a[3] = (short)f2bf(u0.w);
                a[4] = (short)f2bf(u1.x); a[5] = (short)f2bf(u1.y);
                a[6] = (short)f2bf(u1.z); a[7] = (short)f2bf(u1.w);
                const int kb = kk * 32 + kg * 8;
                const short8v b0 = *reinterpret_cast<const short8v*>(bw0 + kb);
                const short8v b1 = *reinterpret_cast<const short8v*>(bw1 + kb);
                acc0 = __builtin_amdgcn_mfma_f32_16x16x32_bf16(a, b0, acc0, 0, 0, 0);
                acc1 = __builtin_amdgcn_mfma_f32_16x16x32_bf16(a, b1, acc1, 0, 0, 0);
            }

#pragma unroll
            for (int r = 0; r < 4; ++r) {
                const int sl = tb0 + kg * 4 + r;
                if (sl < ce) {
                    const int row = tl[sl];
                    float* op = out + (size_t)row * DOUT + obase;
                    op[a15]      = acc0[r] + bv0;
                    op[16 + a15] = acc1[r] + bv1;
                }
            }
        }
    }
}

extern "C" void kernel_launch(void* const* d_in, const int* in_sizes, int n_in,
                              void* d_out, int out_size, void* d_ws, size_t ws_size,
                              hipStream_t stream) {
    const float* x      = (const float*)d_in[0];
    const int*   index  = (const int*)d_in[1];
    const float* weight = (const float*)d_in[2];
    const float* bias   = (const float*)d_in[3];
    float* out = (float*)d_out;

    int* cnt            = (int*)d_ws;                               // 32 ints
    unsigned short* tok = (unsigned short*)((char*)d_ws + 256);     // 32 x 4096 u16

    route_kernel<<<NE, 256, 0, stream>>>(index, cnt, tok);
    // 4 splits x 8 col-slices x 32 experts = 1024 blocks; bx%8 = e%8 (XCD)
    gemm_kernel<<<SPL * 8 * NE, 256, 0, stream>>>(x, weight, bias, cnt, tok, out);
}

// Round 14
// 23.411 us; speedup vs baseline: 2.2050x; 2.2050x over previous
//
#include <hip/hip_runtime.h>

#define NE    32
#define DIN   256
#define DOUT  256

typedef __attribute__((ext_vector_type(8))) short short8v;   // 8 bf16 = 4 VGPR
typedef __attribute__((ext_vector_type(4))) float float4v;   // MFMA accumulator

__device__ __forceinline__ unsigned short f2bf(float f) {
    // fp32 -> bf16 round-to-nearest-even (inputs finite); verified R10 (absmax 0.031)
    unsigned u = __float_as_uint(f);
    return (unsigned short)((u + 0x7FFFu + ((u >> 16) & 1u)) >> 16);
}

// prep: role-split single launch.
//   block 0        : routing -> sorted[4096] (u16) + packed group table groups[288]
//                    (e<<17 | m<<12 | start; sentinel 0xFFFFFFFF). Within-expert
//                    order is atomic-nondeterministic, but every token's output is
//                    computed identically regardless of slot -> deterministic output.
//   blocks 1..512  : x (fp32) -> x16 (bf16), coalesced
//   blocks 513..1024: w (fp32 [e][k][c]) -> wt (bf16 [e][c][k]), LDS-tiled transpose
__global__ __launch_bounds__(256) void prep_kernel(
    const float* __restrict__ x, const int* __restrict__ idx, const float* __restrict__ w,
    unsigned short* __restrict__ sorted, unsigned int* __restrict__ groups,
    unsigned short* __restrict__ x16, unsigned short* __restrict__ wt)
{
    const int bx = blockIdx.x, tid = threadIdx.x;

    if (bx == 0) {
        __shared__ int cnt[NE], offs[NE], pos[NE], goff[NE + 1];
        if (tid < NE) { cnt[tid] = 0; pos[tid] = 0; }
        __syncthreads();

        int4 v[4];
#pragma unroll
        for (int r = 0; r < 4; ++r) {
            const int tb = r * 1024 + tid * 4;
            v[r] = *reinterpret_cast<const int4*>(idx + tb);
            atomicAdd(&cnt[v[r].x], 1); atomicAdd(&cnt[v[r].y], 1);
            atomicAdd(&cnt[v[r].z], 1); atomicAdd(&cnt[v[r].w], 1);
        }
        __syncthreads();

        if (tid == 0) {
            int run = 0, grun = 0;
            for (int e = 0; e < NE; ++e) {
                offs[e] = run; goff[e] = grun;
                run += cnt[e]; grun += (cnt[e] + 15) >> 4;
            }
            goff[NE] = grun;
        }
        __syncthreads();

        // group table (thread e writes its expert's groups)
        if (tid < NE) {
            const int ce = cnt[tid], o = offs[tid], go = goff[tid];
            for (int j = 0; j * 16 < ce; ++j)
                groups[go + j] = ((unsigned)tid << 17) |
                                 ((unsigned)min(16, ce - j * 16) << 12) |
                                 (unsigned)(o + j * 16);
        }
        const int G = goff[NE];
        for (int g = tid; g < 288; g += 256)
            if (g >= G) groups[g] = 0xFFFFFFFFu;

        // scatter token ids
#pragma unroll
        for (int r = 0; r < 4; ++r) {
            const int tb = r * 1024 + tid * 4;
            int p;
            p = atomicAdd(&pos[v[r].x], 1); sorted[offs[v[r].x] + p] = (unsigned short)(tb + 0);
            p = atomicAdd(&pos[v[r].y], 1); sorted[offs[v[r].y] + p] = (unsigned short)(tb + 1);
            p = atomicAdd(&pos[v[r].z], 1); sorted[offs[v[r].z] + p] = (unsigned short)(tb + 2);
            p = atomicAdd(&pos[v[r].w], 1); sorted[offs[v[r].w] + p] = (unsigned short)(tb + 3);
        }
    } else if (bx <= 512) {
        // x -> bf16: 8 floats per thread, coalesced in and out
        const int i8 = (bx - 1) * 256 + tid;   // unit = 8 elements
        const float4 u0 = *reinterpret_cast<const float4*>(x + (size_t)i8 * 8);
        const float4 u1 = *reinterpret_cast<const float4*>(x + (size_t)i8 * 8 + 4);
        uint4 pk;
        pk.x = (unsigned)f2bf(u0.x) | ((unsigned)f2bf(u0.y) << 16);
        pk.y = (unsigned)f2bf(u0.z) | ((unsigned)f2bf(u0.w) << 16);
        pk.z = (unsigned)f2bf(u1.x) | ((unsigned)f2bf(u1.y) << 16);
        pk.w = (unsigned)f2bf(u1.z) | ((unsigned)f2bf(u1.w) << 16);
        *reinterpret_cast<uint4*>(x16 + (size_t)i8 * 8) = pk;
    } else {
        // w[e][k][c] -> wt[e][c][k], 64x64 tile via LDS
        __shared__ unsigned short lt[64][72];   // +8 pad
        const int b2 = bx - 513;
        const int e = b2 >> 4, t = b2 & 15, kt = t >> 2, ct = t & 3;
        const float* wb = w + ((size_t)e * DIN + kt * 64) * DOUT + ct * 64;
#pragma unroll
        for (int p = 0; p < 4; ++p) {
            const int k  = p * 16 + (tid >> 4);
            const int c4 = (tid & 15) * 4;
            const float4 q = *reinterpret_cast<const float4*>(wb + (size_t)k * DOUT + c4);
            lt[c4 + 0][k] = f2bf(q.x); lt[c4 + 1][k] = f2bf(q.y);
            lt[c4 + 2][k] = f2bf(q.z); lt[c4 + 3][k] = f2bf(q.w);
        }
        __syncthreads();
        const int c = tid >> 2, kb = (tid & 3) * 16;
        const uint4 o0 = *reinterpret_cast<const uint4*>(&lt[c][kb]);
        const uint4 o1 = *reinterpret_cast<const uint4*>(&lt[c][kb + 8]);
        unsigned short* dst = wt + ((size_t)e * DOUT + ct * 64 + c) * DIN + kt * 64 + kb;
        *reinterpret_cast<uint4*>(dst)     = o0;
        *reinterpret_cast<uint4*>(dst + 8) = o1;
    }
}

// gemm: one wave = one (group, col-slice). No LDS, no barriers, no loops.
// W panel lives in 64 VGPRs (B-frags from wt), A-frags = 8 dwordx4 from x16.
// Fragment mapping identical to R10-verified kernel.
__global__ __launch_bounds__(256) void gemm_kernel(
    const unsigned short* __restrict__ x16, const unsigned short* __restrict__ wt,
    const float* __restrict__ bias,
    const unsigned short* __restrict__ sorted, const unsigned int* __restrict__ groups,
    float* __restrict__ out)
{
    const int wid = threadIdx.x >> 6, lane = threadIdx.x & 63;
    const unsigned g8 = blockIdx.x * 4 + wid;
    const unsigned g = g8 >> 3, cb = g8 & 7;
    const unsigned grp = groups[g];
    if (grp == 0xFFFFFFFFu) return;   // wave-uniform exit (no barriers in kernel)

    const int e     = grp >> 17;
    const int m     = (grp >> 12) & 31;
    const int start = grp & 4095;
    const int obase = cb * 32;
    const int a15   = lane & 15;
    const int kg    = lane >> 4;

    // B: col = a15 (+16), k = kk*32 + kg*8 .. +7 (contiguous bf16 in wt)
    const unsigned short* wtb = wt + ((size_t)e * DOUT + obase) * DIN;
    short8v b0[8], b1[8];
#pragma unroll
    for (int kk = 0; kk < 8; ++kk) {
        b0[kk] = *reinterpret_cast<const short8v*>(wtb + a15 * DIN + kk * 32 + kg * 8);
        b1[kk] = *reinterpret_cast<const short8v*>(wtb + (16 + a15) * DIN + kk * 32 + kg * 8);
    }
    const float bv0 = bias[(size_t)e * DOUT + obase + a15];
    const float bv1 = bias[(size_t)e * DOUT + obase + 16 + a15];

    // A: row = a15 <-> token sorted[start + a15]
    const int tok = sorted[start + min(a15, m - 1)];
    const unsigned short* xr = x16 + (size_t)tok * DIN + kg * 8;
    short8v a[8];
#pragma unroll
    for (int kk = 0; kk < 8; ++kk)
        a[kk] = *reinterpret_cast<const short8v*>(xr + kk * 32);

    float4v acc0 = {0.f, 0.f, 0.f, 0.f};
    float4v acc1 = {0.f, 0.f, 0.f, 0.f};
#pragma unroll
    for (int kk = 0; kk < 8; ++kk) {
        acc0 = __builtin_amdgcn_mfma_f32_16x16x32_bf16(a[kk], b0[kk], acc0, 0, 0, 0);
        acc1 = __builtin_amdgcn_mfma_f32_16x16x32_bf16(a[kk], b1[kk], acc1, 0, 0, 0);
    }

    // D: row = kg*4 + r <-> token sorted[start + kg*4 + r]
#pragma unroll
    for (int r = 0; r < 4; ++r) {
        const int sl = kg * 4 + r;
        if (sl < m) {
            const int row = sorted[start + sl];
            float* op = out + (size_t)row * DOUT + obase;
            op[a15]      = acc0[r] + bv0;
            op[16 + a15] = acc1[r] + bv1;
        }
    }
}

extern "C" void kernel_launch(void* const* d_in, const int* in_sizes, int n_in,
                              void* d_out, int out_size, void* d_ws, size_t ws_size,
                              hipStream_t stream) {
    const float* x      = (const float*)d_in[0];
    const int*   index  = (const int*)d_in[1];
    const float* weight = (const float*)d_in[2];
    const float* bias   = (const float*)d_in[3];
    float* out = (float*)d_out;

    unsigned short* sorted = (unsigned short*)d_ws;                               // 4096 u16
    unsigned int*   groups = (unsigned int*)((char*)d_ws + 8192);                 // 288 u32
    unsigned short* x16    = (unsigned short*)((char*)d_ws + 16384);              // 1M u16 (2 MB)
    unsigned short* wt     = (unsigned short*)((char*)d_ws + 16384 + 2097152);    // 2M u16 (4 MB)

    // 1 routing block + 512 x-convert blocks + 512 w-transpose blocks
    prep_kernel<<<1025, 256, 0, stream>>>(x, index, weight, sorted, groups, x16, wt);
    // 288 groups x 8 col-slices = 2304 waves = 576 blocks
    gemm_kernel<<<576, 256, 0, stream>>>(x16, wt, bias, sorted, groups, out);
}

// Round 16
// 13.958 us; speedup vs baseline: 3.6983x; 1.6773x over previous
//
#include <hip/hip_runtime.h>

#define NE    32
#define DIN   256
#define DOUT  256
#define TN    32     // output cols per block
#define SPL   4      // token-split factor

typedef __attribute__((ext_vector_type(8))) short short8v;   // 8 bf16 = 4 VGPR
typedef __attribute__((ext_vector_type(4))) float float4v;   // MFMA accumulator

__device__ __forceinline__ unsigned short f2bf(float f) {
    // fp32 -> bf16 round-to-nearest-even; PROVEN R10-R14 (absmax 0.03125)
    unsigned u = __float_as_uint(f);
    return (unsigned short)((u + 0x7FFFu + ((u >> 16) & 1u)) >> 16);
}
__device__ __forceinline__ unsigned pk2(float lo, float hi) {
    return (unsigned)f2bf(lo) | ((unsigned)f2bf(hi) << 16);
}

// Fused MFMA MoE v4b == R15 with the hand-written v_cvt_pk_bf16_f32 asm
// REVERTED to proven f2bf (guide T12: "don't hand-write cvt_pk"). Keeps:
//  - fragment-major wls[(kk*2+h)*64+lane]: conflict-free b128 B-frag reads
//  - sched_barrier(0) after the 16-load x batch: forces loads in flight
__global__ __launch_bounds__(256, 4) void moe_mfma_kernel(
    const float* __restrict__ x, const int* __restrict__ idx,
    const float* __restrict__ w, const float* __restrict__ bias,
    float* __restrict__ out)
{
    __shared__ unsigned short wls[16 * 64 * 8];   // 16 KB, fragment-major [kk*2+h][lane][i]
    __shared__ unsigned short toklist[4096];      //  8 KB
    __shared__ int wcnt[4][4];                    // [round][wave]

    const int tid   = threadIdx.x;
    const int e     = blockIdx.x & 31;          // expert; XCD = bx%8 = e%8
    const int cb    = (blockIdx.x >> 5) & 7;    // col slice
    const int s     = blockIdx.x >> 8;          // token split 0..3
    const int obase = cb * TN;
    const int lane  = tid & 63;
    const int wid   = tid >> 6;
    const unsigned long long lt = (1ull << lane) - 1ull;

    // ---- load all indices up front (4 int4/thread) ----
    int4 v0 = *reinterpret_cast<const int4*>(idx + 0 * 1024 + tid * 4);
    int4 v1 = *reinterpret_cast<const int4*>(idx + 1 * 1024 + tid * 4);
    int4 v2 = *reinterpret_cast<const int4*>(idx + 2 * 1024 + tid * 4);
    int4 v3 = *reinterpret_cast<const int4*>(idx + 3 * 1024 + tid * 4);

    // ---- collect: deterministic ballot-scan (R12-proven), 1 barrier/round ----
    int running = 0;
#define ROUND(vv, r)                                                                   \
    {                                                                                  \
        const int tb = (r) * 1024 + tid * 4;                                           \
        const unsigned long long m0 = __ballot((vv).x == e);                           \
        const unsigned long long m1 = __ballot((vv).y == e);                           \
        const unsigned long long m2 = __ballot((vv).z == e);                           \
        const unsigned long long m3 = __ballot((vv).w == e);                           \
        const int p0 = __popcll(m0), p1 = __popcll(m1), p2 = __popcll(m2), p3 = __popcll(m3); \
        if (lane == 0) wcnt[r][wid] = p0 + p1 + p2 + p3;                               \
        __syncthreads();                                                               \
        int wb = running;                                                              \
        if (wid > 0) wb += wcnt[r][0];                                                 \
        if (wid > 1) wb += wcnt[r][1];                                                 \
        if (wid > 2) wb += wcnt[r][2];                                                 \
        const int b0 = wb, b1 = b0 + p0, b2 = b1 + p1, b3 = b2 + p2;                   \
        if ((vv).x == e) toklist[b0 + __popcll(m0 & lt)] = (unsigned short)(tb + 0);   \
        if ((vv).y == e) toklist[b1 + __popcll(m1 & lt)] = (unsigned short)(tb + 1);   \
        if ((vv).z == e) toklist[b2 + __popcll(m2 & lt)] = (unsigned short)(tb + 2);   \
        if ((vv).w == e) toklist[b3 + __popcll(m3 & lt)] = (unsigned short)(tb + 3);   \
        running += wcnt[r][0] + wcnt[r][1] + wcnt[r][2] + wcnt[r][3];                  \
    }
    ROUND(v0, 0) ROUND(v1, 1) ROUND(v2, 2) ROUND(v3, 3)
#undef ROUND
    const int ce = running;
    if (ce <= s * 64) return;   // block-uniform: this split has no token groups

    // ---- stage W -> bf16 fragment-major: 1024 frags, 4 per thread, b128 writes ----
    // frag(kk,h,l) element i = W[kk*32 + (l>>4)*8 + i][obase + h*16 + (l&15)]
#pragma unroll
    for (int f = 0; f < 4; ++f) {
        const int fid   = f * 256 + tid;
        const int k2h   = fid >> 6;      // kk*2+h
        const int lp    = fid & 63;
        const int kbase = (k2h >> 1) * 32 + (lp >> 4) * 8;
        const int c     = obase + (k2h & 1) * 16 + (lp & 15);
        const float* wp = w + (size_t)e * DIN * DOUT + (size_t)kbase * DOUT + c;
        float q[8];
#pragma unroll
        for (int i = 0; i < 8; ++i) q[i] = wp[(size_t)i * DOUT];
        uint4 pk;
        pk.x = pk2(q[0], q[1]);
        pk.y = pk2(q[2], q[3]);
        pk.z = pk2(q[4], q[5]);
        pk.w = pk2(q[6], q[7]);
        *reinterpret_cast<uint4*>(&wls[(size_t)(k2h * 64 + lp) * 8]) = pk;
    }
    __syncthreads();   // covers round-3 toklist writes + W stage

    // fragment lane roles (16x16x32 bf16, R10-verified):
    //   A: row = lane&15 (token slot), k = (lane>>4)*8 + i
    //   B: col = lane&15, k = (lane>>4)*8 + i   (= frag(kk,h,lane) content)
    //   C/D: col = lane&15, row = (lane>>4)*4 + reg
    const int a15 = lane & 15;
    const int kg  = lane >> 4;
    const float bv0 = bias[(size_t)e * DOUT + obase + a15];
    const float bv1 = bias[(size_t)e * DOUT + obase + 16 + a15];

#pragma unroll 1
    for (int tb0 = (s * 4 + wid) * 16; tb0 < ce; tb0 += SPL * 64) {
        const int tok = toklist[min(tb0 + a15, ce - 1)];
        const float* xr = x + (size_t)tok * DIN + kg * 8;

        float4 L[16];
#pragma unroll
        for (int kk = 0; kk < 8; ++kk) {
            L[2 * kk]     = *reinterpret_cast<const float4*>(xr + kk * 32);
            L[2 * kk + 1] = *reinterpret_cast<const float4*>(xr + kk * 32 + 4);
        }
        __builtin_amdgcn_sched_barrier(0);   // all 16 loads issue before any use

        float4v acc0 = {0.f, 0.f, 0.f, 0.f};
        float4v acc1 = {0.f, 0.f, 0.f, 0.f};
#pragma unroll
        for (int kk = 0; kk < 8; ++kk) {
            uint4 ua;
            ua.x = pk2(L[2 * kk].x,     L[2 * kk].y);
            ua.y = pk2(L[2 * kk].z,     L[2 * kk].w);
            ua.z = pk2(L[2 * kk + 1].x, L[2 * kk + 1].y);
            ua.w = pk2(L[2 * kk + 1].z, L[2 * kk + 1].w);
            const short8v a  = __builtin_bit_cast(short8v, ua);
            const short8v b0 = *reinterpret_cast<const short8v*>(&wls[((kk * 2 + 0) * 64 + lane) * 8]);
            const short8v b1 = *reinterpret_cast<const short8v*>(&wls[((kk * 2 + 1) * 64 + lane) * 8]);
            acc0 = __builtin_amdgcn_mfma_f32_16x16x32_bf16(a, b0, acc0, 0, 0, 0);
            acc1 = __builtin_amdgcn_mfma_f32_16x16x32_bf16(a, b1, acc1, 0, 0, 0);
        }

#pragma unroll
        for (int r = 0; r < 4; ++r) {
            const int sl = tb0 + kg * 4 + r;
            if (sl < ce) {
                const int row = toklist[sl];
                float* op = out + (size_t)row * DOUT + obase;
                op[a15]      = acc0[r] + bv0;
                op[16 + a15] = acc1[r] + bv1;
            }
        }
    }
}

extern "C" void kernel_launch(void* const* d_in, const int* in_sizes, int n_in,
                              void* d_out, int out_size, void* d_ws, size_t ws_size,
                              hipStream_t stream) {
    const float* x      = (const float*)d_in[0];
    const int*   index  = (const int*)d_in[1];
    const float* weight = (const float*)d_in[2];
    const float* bias   = (const float*)d_in[3];
    float* out = (float*)d_out;

    // 4 splits x 8 col-slices x 32 experts = 1024 blocks = 4/CU; bx%8 = e%8 (XCD)
    moe_mfma_kernel<<<SPL * 8 * NE, 256, 0, stream>>>(x, index, weight, bias, out);
}